// Round 7
// baseline (150.892 us; speedup 1.0000x reference)
//
#include <hip/hip_runtime.h>
#include <hip/hip_bf16.h>
#include <stdint.h>

typedef __attribute__((ext_vector_type(8))) short short8;
typedef __attribute__((ext_vector_type(4))) float floatx4;

typedef const __attribute__((address_space(1))) void* gvp;
typedef __attribute__((address_space(3))) void* lvp;

__device__ __forceinline__ unsigned short f2bf(float f) {
    unsigned u = __float_as_uint(f);
    u += 0x7fffu + ((u >> 16) & 1u);   // RNE
    return (unsigned short)(u >> 16);
}

#define BAR()    do { asm volatile("" ::: "memory"); __builtin_amdgcn_s_barrier(); asm volatile("" ::: "memory"); } while (0)
#define WAITL()  do { asm volatile("s_waitcnt lgkmcnt(0)" ::: "memory"); __builtin_amdgcn_sched_barrier(0); } while (0)
#define WAITV4() asm volatile("s_waitcnt vmcnt(4)" ::: "memory")
#define WAITV0() asm volatile("s_waitcnt vmcnt(0)" ::: "memory")
#define WAITV8() asm volatile("s_waitcnt vmcnt(8)" ::: "memory")
#define WAITV16() asm volatile("s_waitcnt vmcnt(16)" ::: "memory")

// ---------------- conversion: X, Wv straight; Wq, Wk transposed (for G) ----------------
__global__ __launch_bounds__(256)
void cvt_all(const float* __restrict__ x, const float* __restrict__ wq,
             const float* __restrict__ wk, const float* __restrict__ wv,
             unsigned short* __restrict__ Xb, unsigned short* __restrict__ WqT,
             unsigned short* __restrict__ WkT, unsigned short* __restrict__ Wvb) {
    const int b = blockIdx.x, t = threadIdx.x;
    if (b < 2304) {
        const float* in; unsigned short* out; long base;
        if (b < 2048) { in = x;  out = Xb;  base = (long)b * 1024; }
        else          { in = wv; out = Wvb; base = (long)(b - 2048) * 1024; }
        #pragma unroll
        for (int k = 0; k < 4; ++k) {
            long idx = base + k * 256 + t;
            float4 v = reinterpret_cast<const float4*>(in)[idx];
            uint2 o;
            o.x = (unsigned)f2bf(v.x) | ((unsigned)f2bf(v.y) << 16);
            o.y = (unsigned)f2bf(v.z) | ((unsigned)f2bf(v.w) << 16);
            reinterpret_cast<uint2*>(out)[idx] = o;
        }
    } else {
        const int bb = b - 2304;
        const float* in = (bb < 256) ? wq : wk;
        unsigned short* out = (bb < 256) ? WqT : WkT;
        const int tile = bb & 255;
        const int e0 = (tile >> 4) * 64, d0 = (tile & 15) * 64;
        __shared__ unsigned short ldsT[64][68];
        const int r = t >> 4, cq = t & 15;
        #pragma unroll
        for (int p = 0; p < 4; ++p) {
            const int e = p * 16 + r;
            float4 v = *reinterpret_cast<const float4*>(in + (long)(e0 + e) * 1024 + d0 + cq * 4);
            ldsT[cq*4+0][e] = f2bf(v.x);
            ldsT[cq*4+1][e] = f2bf(v.y);
            ldsT[cq*4+2][e] = f2bf(v.z);
            ldsT[cq*4+3][e] = f2bf(v.w);
        }
        __syncthreads();
        #pragma unroll
        for (int p = 0; p < 4; ++p) {
            const int d = p * 16 + r;
            ushort4 o = *reinterpret_cast<const ushort4*>(&ldsT[d][cq * 4]);
            *reinterpret_cast<ushort4*>(out + (long)(d0 + d) * 1024 + e0 + cq * 4) = o;
        }
    }
}

// ===================== 128x128 engine pieces (T2 swizzle) =====================
__device__ __forceinline__ void stage_tile(unsigned short* Abuf, unsigned short* Bbuf,
                                           const unsigned short* A, int lda,
                                           const unsigned short* B, int ldb, int k0,
                                           int wid, int srow, int piece) {
    #pragma unroll
    for (int i = 0; i < 4; ++i) {
        const int c = wid * 4 + i;
        const int row = c * 8 + srow;
        const int cs = (piece * 16) ^ ((row & 7) << 4);   // pre-swizzled source col
        __builtin_amdgcn_global_load_lds(
            (gvp)(reinterpret_cast<const char*>(A + (long)row * lda + k0) + cs),
            (lvp)(reinterpret_cast<char*>(Abuf) + c * 1024), 16, 0, 0);
        __builtin_amdgcn_global_load_lds(
            (gvp)(reinterpret_cast<const char*>(B + (long)row * ldb + k0) + cs),
            (lvp)(reinterpret_cast<char*>(Bbuf) + c * 1024), 16, 0, 0);
    }
}

__device__ __forceinline__ void compute_tile(floatx4 acc[4][4], const unsigned short* As,
                                             const unsigned short* Bs, int wm, int wn,
                                             int frow, int lane) {
    #pragma unroll
    for (int ks = 0; ks < 2; ++ks) {
        short8 af[4], bf[4];
        const int colb = ks * 64 + (lane >> 4) * 16;
        #pragma unroll
        for (int i = 0; i < 4; ++i) {
            const int ar = wm + i * 16 + frow;
            af[i] = *reinterpret_cast<const short8*>(
                reinterpret_cast<const char*>(As) + ar * 128 + (colb ^ ((ar & 7) << 4)));
            const int br = wn + i * 16 + frow;
            bf[i] = *reinterpret_cast<const short8*>(
                reinterpret_cast<const char*>(Bs) + br * 128 + (colb ^ ((br & 7) << 4)));
        }
        #pragma unroll
        for (int i = 0; i < 4; ++i)
            #pragma unroll
            for (int j = 0; j < 4; ++j)
                acc[i][j] = __builtin_amdgcn_mfma_f32_16x16x32_bf16(af[i], bf[j], acc[i][j], 0, 0, 0);
    }
}

// ---- G split-K chunk: Gw[bz] += WkT-tile x WqT-tile over k in [bz*256, bz*256+256) ----
__global__ __launch_bounds__(256, 2)
void g_chunk(const unsigned short* __restrict__ WkT, const unsigned short* __restrict__ WqT,
             float* __restrict__ Gw) {
    const int bx = blockIdx.x, by = blockIdx.y, bz = blockIdx.z;
    const unsigned short* A = WkT + (long)by * 128 * 1024;
    const unsigned short* B = WqT + (long)bx * 128 * 1024;

    __shared__ unsigned short As[2][128 * 64];
    __shared__ unsigned short Bs[2][128 * 64];

    const int tid = threadIdx.x, lane = tid & 63, wid = tid >> 6;
    const int srow = lane >> 3, piece = lane & 7;
    const int wm = (wid >> 1) * 64, wn = (wid & 1) * 64, frow = lane & 15;

    floatx4 acc[4][4] = {};
    const int kbase = bz * 256;

    stage_tile(As[0], Bs[0], A, 1024, B, 1024, kbase, wid, srow, piece);
    WAITV0(); BAR();
    int cur = 0;
    #pragma unroll 1
    for (int t = 0; t < 4; ++t) {
        if (t < 3)
            stage_tile(As[cur ^ 1], Bs[cur ^ 1], A, 1024, B, 1024, kbase + (t + 1) * 64,
                       wid, srow, piece);
        compute_tile(acc, As[cur], Bs[cur], wm, wn, frow, lane);
        WAITV0(); BAR();
        cur ^= 1;
    }

    float* Cb = Gw + (long)bz * (1 << 20) + (long)(by * 128) * 1024 + bx * 128;
    const int cr0 = wm + (lane >> 4) * 4;
    const int cc0 = wn + (lane & 15);
    #pragma unroll
    for (int i = 0; i < 4; ++i)
        #pragma unroll
        for (int j = 0; j < 4; ++j)
            #pragma unroll
            for (int r = 0; r < 4; ++r)
                Cb[(long)(cr0 + i * 16 + r) * 1024 + cc0 + j * 16] = acc[i][j][r];
}

// ---- reduce 4 G chunks -> bf16 G (scaled by 1/sqrt(1024)) ----
__global__ __launch_bounds__(256)
void reduce_g(const float* __restrict__ Gw, unsigned short* __restrict__ Gp) {
    const long i4 = (long)blockIdx.x * 256 + threadIdx.x;
    const long M4 = (1l << 20) / 4;
    float4 a = reinterpret_cast<const float4*>(Gw)[i4];
    float4 b = reinterpret_cast<const float4*>(Gw)[i4 + M4];
    float4 c = reinterpret_cast<const float4*>(Gw)[i4 + 2 * M4];
    float4 d = reinterpret_cast<const float4*>(Gw)[i4 + 3 * M4];
    float sx = (a.x + b.x + c.x + d.x) * 0.03125f;
    float sy = (a.y + b.y + c.y + d.y) * 0.03125f;
    float sz = (a.z + b.z + c.z + d.z) * 0.03125f;
    float sw = (a.w + b.w + c.w + d.w) * 0.03125f;
    uint2 o;
    o.x = (unsigned)f2bf(sx) | ((unsigned)f2bf(sy) << 16);
    o.y = (unsigned)f2bf(sz) | ((unsigned)f2bf(sw) << 16);
    reinterpret_cast<uint2*>(Gp)[i4] = o;
}

// ---- PV: complementary pairing + depth-3 prefetch (4 LDS buffers, counted vmcnt) ----
__global__ __launch_bounds__(256, 1)
void pv_pair(const unsigned short* __restrict__ P, const unsigned short* __restrict__ Vt,
             float* __restrict__ out) {
    int flat = (blockIdx.z * 8 + blockIdx.y) * 8 + blockIdx.x;
    { int xcd = flat & 7, lid = flat >> 3; flat = xcd * 32 + lid; }
    const int bx = flat % 8;
    const int pj = (flat / 8) % 8;
    const int bz = flat / 64;

    const unsigned short* Pb = P + (long)bz * 2048 * 4096;   // bf16 view of f32 rows
    const unsigned short* Bv = Vt + (long)bz * 1024 * 2048 + (long)(bx * 128) * 2048;
    float* Cb = out + (long)bz * 2048 * 1024;

    __shared__ unsigned short As[4][128 * 64];   // 64 KiB
    __shared__ unsigned short Bs[4][128 * 64];   // 64 KiB

    const int tid = threadIdx.x, lane = tid & 63, wid = tid >> 6;
    const int srow = lane >> 3, piece = lane & 7;
    const int wm = (wid >> 1) * 64, wn = (wid & 1) * 64, frow = lane & 15;

    #pragma unroll 1
    for (int j = 0; j < 2; ++j) {
        const int by = j ? 15 - pj : pj;
        const unsigned short* A = Pb + (long)by * 128 * 4096;
        const int nt = (by + 1) * 2;   // K-tiles of 64 (>= 2)

        floatx4 acc[4][4] = {};
        // prologue: 3 tiles in flight (reads beyond nt*64 are in-bounds garbage, never used)
        stage_tile(As[0], Bs[0], A, 4096, Bv, 2048, 0,   wid, srow, piece);
        stage_tile(As[1], Bs[1], A, 4096, Bv, 2048, 64,  wid, srow, piece);
        stage_tile(As[2], Bs[2], A, 4096, Bv, 2048, 128, wid, srow, piece);
        WAITV16();    // tile 0 landed (16 = tiles 1,2 still out; also drains prior C-stores)
        BAR();

        #pragma unroll 1
        for (int t = 0; t < nt; ++t) {
            if (t + 3 < nt) {
                stage_tile(As[(t + 3) & 3], Bs[(t + 3) & 3], A, 4096, Bv, 2048,
                           (t + 3) * 64, wid, srow, piece);
                compute_tile(acc, As[t & 3], Bs[t & 3], wm, wn, frow, lane);
                WAITV16();             // tile t+1 landed
            } else {
                compute_tile(acc, As[t & 3], Bs[t & 3], wm, wn, frow, lane);
                if (t + 2 < nt)      { WAITV8(); }   // tiles t+1,t+2 out -> t+1 landed
                else                 { WAITV0(); }   // drain tail
            }
            BAR();
        }

        float* Cj = Cb + (long)(by * 128) * 1024 + bx * 128;
        const int cr0 = wm + (lane >> 4) * 4;
        const int cc0 = wn + (lane & 15);
        #pragma unroll
        for (int i = 0; i < 4; ++i)
            #pragma unroll
            for (int jj = 0; jj < 4; ++jj)
                #pragma unroll
                for (int r = 0; r < 4; ++r)
                    Cj[(long)(cr0 + i * 16 + r) * 1024 + cc0 + jj * 16] = acc[i][jj][r];
    }
}

// ===================== 256x256 8-phase GEMM (unchanged engine) =====================
__device__ __forceinline__ void stage_half(char* slot, const unsigned short* src,
                                           int ld, int k0, int tid) {
    #pragma unroll
    for (int r = 0; r < 2; ++r) {
        const int c = r * 512 + tid;
        const int row = c >> 3;
        const int cs = ((c & 7) * 16) ^ ((row & 7) << 4);
        const char* g = reinterpret_cast<const char*>(src + (long)row * ld + k0) + cs;
        __builtin_amdgcn_global_load_lds((gvp)g,
            (lvp)(slot + r * 8192 + (tid >> 6) * 1024), 16, 0, 0);
    }
}

__device__ __forceinline__ void load_a4(short8 a_[4][2], const char* slot, int mh,
                                        int fr, int csw0, int csw1) {
    #pragma unroll
    for (int i = 0; i < 4; ++i) {
        const int rb = (mh * 64 + i * 16 + fr) * 128;
        a_[i][0] = *reinterpret_cast<const short8*>(slot + rb + csw0);
        a_[i][1] = *reinterpret_cast<const short8*>(slot + rb + csw1);
    }
}

__device__ __forceinline__ void load_b2(short8 b_[2][2], const char* slot, int rbase,
                                        int nh, int fr, int csw0, int csw1) {
    #pragma unroll
    for (int j = 0; j < 2; ++j) {
        const int rb = (rbase + nh * 32 + j * 16 + fr) * 128;
        b_[j][0] = *reinterpret_cast<const short8*>(slot + rb + csw0);
        b_[j][1] = *reinterpret_cast<const short8*>(slot + rb + csw1);
    }
}

__device__ __forceinline__ void mfma16(floatx4 acc[8][4], short8 a_[4][2],
                                       short8 b_[2][2], int mh, int nh) {
    __builtin_amdgcn_s_setprio(1);
    #pragma unroll
    for (int i = 0; i < 4; ++i)
        #pragma unroll
        for (int j = 0; j < 2; ++j) {
            acc[mh*4+i][nh*2+j] = __builtin_amdgcn_mfma_f32_16x16x32_bf16(
                a_[i][0], b_[j][0], acc[mh*4+i][nh*2+j], 0, 0, 0);
            acc[mh*4+i][nh*2+j] = __builtin_amdgcn_mfma_f32_16x16x32_bf16(
                a_[i][1], b_[j][1], acc[mh*4+i][nh*2+j], 0, 0, 0);
        }
    __builtin_amdgcn_s_setprio(0);
}

template<typename CT, int MODE>
__global__ __launch_bounds__(512, 2)
void gemm8p(const unsigned short* __restrict__ A, const unsigned short* B,
            const unsigned short* B1, CT* __restrict__ C, unsigned short* __restrict__ Vt,
            int K, int lda, int ldb, int ldc,
            long sA, long sB, long sC, int nwg)
{
    const int gx = gridDim.x, gy = gridDim.y;
    int flat = (blockIdx.z * gy + blockIdx.y) * gx + blockIdx.x;
    {
        int xcd = flat & 7, lid = flat >> 3;
        int q = nwg >> 3, r = nwg & 7;
        flat = (xcd < r ? xcd * (q + 1) : r * (q + 1) + (xcd - r) * q) + lid;
    }
    int bx, by, bz = 0;
    bool isV = false;
    if (MODE == 1) {
        bx = flat % gx;
        int t2 = flat / gx;
        by = t2 % gy;
        bz = t2 / gy;
        if (bx > by) return;
    } else {            // MODE 3: dual job
        if (flat >= 128) { isV = true; flat -= 128; B = B1; }
        by = flat >> 2;
        bx = flat & 3;
    }

    A += (long)bz * sA + (long)by * 256 * lda;
    B += (long)bz * sB + (long)bx * 256 * ldb;
    C += (long)bz * sC;

    __shared__ __align__(16) char lds[8 * 16384];
    #define SLOT(db, op, half) (lds + ((((db) << 1 | (op)) << 1 | (half)) * 16384))

    const int tid  = threadIdx.x;
    const int lane = tid & 63;
    const int wid  = tid >> 6;
    const int wm = wid >> 2;
    const int wn = wid & 3;
    const int bh = wn >> 1;
    const int brbase = (wn & 1) * 64;
    const int fr = lane & 15;
    const int csw0 = ((lane >> 4) * 16) ^ ((fr & 7) << 4);
    const int csw1 = (64 + (lane >> 4) * 16) ^ ((fr & 7) << 4);

    const unsigned short* Ah[2] = { A, A + 128ll * lda };
    const unsigned short* Bh[2] = { B, B + 128ll * ldb };

    const int NT = K >> 6;
    const int NI = NT >> 1;

    floatx4 acc[8][4] = {};
    short8 a_[4][2];
    short8 b_[2][2][2];

    stage_half(SLOT(0,1,0), Bh[0], ldb, 0, tid);
    stage_half(SLOT(0,1,1), Bh[1], ldb, 0, tid);
    stage_half(SLOT(0,0,0), Ah[0], lda, 0, tid);
    stage_half(SLOT(0,0,1), Ah[1], lda, 0, tid);
    stage_half(SLOT(1,1,0), Bh[0], ldb, 64, tid);
    stage_half(SLOT(1,1,1), Bh[1], ldb, 64, tid);
    WAITV4();
    BAR();

    for (int I = 0; I < NI; ++I) {
        const int kA1 = min(2*I + 1, NT - 1) * 64;
        const int kT2 = min(2*I + 2, NT - 1) * 64;
        const int kB3 = min(2*I + 3, NT - 1) * 64;

        load_a4(a_, SLOT(0,0,wm), 0, fr, csw0, csw1);
        load_b2(b_[0], SLOT(0,1,bh), brbase, 0, fr, csw0, csw1);
        stage_half(SLOT(1,0,0), Ah[0], lda, kA1, tid);
        BAR(); WAITL();
        mfma16(acc, a_, b_[0], 0, 0);
        BAR();

        load_b2(b_[1], SLOT(0,1,bh), brbase, 1, fr, csw0, csw1);
        stage_half(SLOT(1,0,1), Ah[1], lda, kA1, tid);
        BAR(); WAITL();
        mfma16(acc, a_, b_[1], 0, 1);
        BAR();

        load_a4(a_, SLOT(0,0,wm), 1, fr, csw0, csw1);
        stage_half(SLOT(0,1,0), Bh[0], ldb, kT2, tid);
        BAR(); WAITL();
        mfma16(acc, a_, b_[1], 1, 1);
        BAR();

        stage_half(SLOT(0,1,1), Bh[1], ldb, kT2, tid);
        BAR(); WAITL();
        mfma16(acc, a_, b_[0], 1, 0);
        WAITV4();
        BAR();

        load_a4(a_, SLOT(1,0,wm), 0, fr, csw0, csw1);
        load_b2(b_[0], SLOT(1,1,bh), brbase, 0, fr, csw0, csw1);
        stage_half(SLOT(0,0,0), Ah[0], lda, kT2, tid);
        BAR(); WAITL();
        mfma16(acc, a_, b_[0], 0, 0);
        BAR();

        load_b2(b_[1], SLOT(1,1,bh), brbase, 1, fr, csw0, csw1);
        stage_half(SLOT(0,0,1), Ah[1], lda, kT2, tid);
        BAR(); WAITL();
        mfma16(acc, a_, b_[1], 0, 1);
        BAR();

        load_a4(a_, SLOT(1,0,wm), 1, fr, csw0, csw1);
        stage_half(SLOT(1,1,0), Bh[0], ldb, kB3, tid);
        BAR(); WAITL();
        mfma16(acc, a_, b_[1], 1, 1);
        BAR();

        stage_half(SLOT(1,1,1), Bh[1], ldb, kB3, tid);
        BAR(); WAITL();
        mfma16(acc, a_, b_[0], 1, 0);
        WAITV4();
        BAR();
    }

    if (MODE == 3 && isV) {
        WAITV0();
        BAR();
        char* T = lds;
        #pragma unroll
        for (int i = 0; i < 8; ++i)
            #pragma unroll
            for (int j = 0; j < 4; ++j) {
                const int n = wn * 64 + j * 16 + fr;
                const int m = wm * 128 + ((lane >> 4) << 2) + i * 16;
                uint2 pk;
                pk.x = (unsigned)f2bf(acc[i][j][0]) | ((unsigned)f2bf(acc[i][j][1]) << 16);
                pk.y = (unsigned)f2bf(acc[i][j][2]) | ((unsigned)f2bf(acc[i][j][3]) << 16);
                *reinterpret_cast<uint2*>(T + n * 512 + ((m * 2) ^ ((n & 7) << 4))) = pk;
            }
        __syncthreads();
        const int b  = by >> 3;
        const int s0 = (by & 7) * 256;
        #pragma unroll
        for (int c = 0; c < 16; ++c) {
            const int idx = c * 512 + tid;
            const int n = idx >> 5, k = idx & 31;
            uint4 v = *reinterpret_cast<const uint4*>(T + n * 512 + ((k * 16) ^ ((n & 7) << 4)));
            *reinterpret_cast<uint4*>(Vt + (long)b * (1024 * 2048)
                + (long)(bx * 256 + n) * 2048 + s0 + k * 8) = v;
        }
        return;
    }

    const int cr0 = by * 256 + wm * 128 + (lane >> 4) * 4;
    const int cc0 = bx * 256 + wn * 64 + (lane & 15);
    #pragma unroll
    for (int i = 0; i < 8; ++i)
        #pragma unroll
        for (int j = 0; j < 4; ++j)
            #pragma unroll
            for (int r = 0; r < 4; ++r) {
                long idx = (long)(cr0 + i * 16 + r) * ldc + (cc0 + j * 16);
                float v = acc[i][j][r];
                if constexpr (sizeof(CT) == 4) C[idx] = v;
                else                           C[idx] = (CT)f2bf(v);
            }
    #undef SLOT
}

// ---------------- causal softmax, row-paired (q, 2047-q): uniform work ----------------
__global__ __launch_bounds__(256)
void softmax_causal(float* __restrict__ Sc) {
    const int b = blockIdx.y;
    const int t = threadIdx.x;
    const int lane = t & 63, wid = t >> 6;
    __shared__ float rmax[2][4], rsum[2][4];

    #pragma unroll 1
    for (int h = 0; h < 2; ++h) {
        const int q = h ? 2047 - blockIdx.x : blockIdx.x;
        float* row = Sc + ((long)b * 2048 + q) * 2048;
        const int kend = (q | 127) + 1;

        float vals[8];
        float mx = -INFINITY;
        #pragma unroll
        for (int i = 0; i < 2; ++i) {
            const int c0 = i * 1024 + t * 4;
            if (c0 <= q) {
                float4 v = *reinterpret_cast<const float4*>(row + c0);
                float tmp[4] = {v.x, v.y, v.z, v.w};
                #pragma unroll
                for (int j = 0; j < 4; ++j) {
                    float val = (c0 + j <= q) ? tmp[j] : -INFINITY;
                    vals[i * 4 + j] = val;
                    mx = fmaxf(mx, val);
                }
            } else {
                vals[i*4+0] = vals[i*4+1] = vals[i*4+2] = vals[i*4+3] = -INFINITY;
            }
        }
        #pragma unroll
        for (int o = 32; o > 0; o >>= 1) mx = fmaxf(mx, __shfl_xor(mx, o));
        if (lane == 0) rmax[h][wid] = mx;
        __syncthreads();
        mx = fmaxf(fmaxf(rmax[h][0], rmax[h][1]), fmaxf(rmax[h][2], rmax[h][3]));

        float s = 0.f;
        #pragma unroll
        for (int k = 0; k < 8; ++k) {
            float e = __expf(vals[k] - mx);
            vals[k] = e;
            s += e;
        }
        #pragma unroll
        for (int o = 32; o > 0; o >>= 1) s += __shfl_xor(s, o);
        if (lane == 0) rsum[h][wid] = s;
        __syncthreads();
        s = rsum[h][0] + rsum[h][1] + rsum[h][2] + rsum[h][3];
        const float inv = 1.f / s;

        unsigned short* orow = reinterpret_cast<unsigned short*>(row);
        #pragma unroll
        for (int i = 0; i < 2; ++i) {
            const int c0 = i * 1024 + t * 4;
            if (c0 < kend) {
                uint2 o;
                o.x = (unsigned)f2bf(vals[i*4+0] * inv) | ((unsigned)f2bf(vals[i*4+1] * inv) << 16);
                o.y = (unsigned)f2bf(vals[i*4+2] * inv) | ((unsigned)f2bf(vals[i*4+3] * inv) << 16);
                *reinterpret_cast<uint2*>(orow + c0) = o;
            }
        }
    }
}

extern "C" void kernel_launch(void* const* d_in, const int* in_sizes, int n_in,
                              void* d_out, int out_size, void* d_ws, size_t ws_size,
                              hipStream_t stream) {
    const float* x  = (const float*)d_in[0];
    const float* Wq = (const float*)d_in[1];
    const float* Wk = (const float*)d_in[2];
    const float* Wv = (const float*)d_in[3];
    float* out = (float*)d_out;

    // ws: Xb@0(16M) WqT@16M(2M) WkT@18M(2M) Wvb@20M(2M) Yb@22M(16M) G@38M(2M)
    //     Gw@40M(16M f32 partials) Vt@70M(16M) Sc@86M(64M)
    char* w = (char*)d_ws;
    unsigned short* Xb  = (unsigned short*)(w);
    unsigned short* WqT = (unsigned short*)(w + (16ll << 20));
    unsigned short* WkT = (unsigned short*)(w + (18ll << 20));
    unsigned short* Wvb = (unsigned short*)(w + (20ll << 20));
    unsigned short* Yb  = (unsigned short*)(w + (22ll << 20));
    unsigned short* Gp  = (unsigned short*)(w + (38ll << 20));
    float*          Gw  = (float*)(w + (40ll << 20));
    unsigned short* Vt  = (unsigned short*)(w + (70ll << 20));
    float* Sc = (float*)(w + (86ll << 20));

    dim3 blk(256);
    cvt_all<<<2816, blk, 0, stream>>>(x, Wq, Wk, Wv, Xb, WqT, WkT, Wvb);

    // G^T = (Wk^T Wq) split-K over 4 chunks, then reduce+scale to bf16
    g_chunk<<<dim3(8, 8, 4), blk, 0, stream>>>(WkT, WqT, Gw);
    reduce_g<<<1024, blk, 0, stream>>>(Gw, Gp);

    // Y = X*G AND V-proj (transposed write) in ONE 256-block 8-phase dispatch
    gemm8p<unsigned short, 3><<<dim3(256, 1, 1), dim3(512), 0, stream>>>(
        Xb, Gp, Wvb, Yb, Vt, 1024, 1024, 1024, 1024,
        0, 0, 0, 256);

    // scores = Y @ X^T (pre-scaled), causal tile skip
    gemm8p<float, 1><<<dim3(8, 8, 4), dim3(512), 0, stream>>>(
        Yb, Xb, nullptr, Sc, nullptr, 1024, 1024, 1024, 2048,
        2048ll * 1024, 2048ll * 1024, 2048ll * 2048, 256);

    softmax_causal<<<dim3(1024, 4), blk, 0, stream>>>(Sc);

    // out = P @ V  (complementary-paired, depth-3 prefetch, uniform 34 K-steps)
    pv_pair<<<dim3(8, 8, 4), blk, 0, stream>>>((const unsigned short*)Sc, Vt, out);
}

// Round 8
// 143.663 us; speedup vs baseline: 1.0503x; 1.0503x over previous
//
#include <hip/hip_runtime.h>
#include <hip/hip_bf16.h>
#include <stdint.h>

typedef __attribute__((ext_vector_type(8))) short short8;
typedef __attribute__((ext_vector_type(4))) float floatx4;

typedef const __attribute__((address_space(1))) void* gvp;
typedef __attribute__((address_space(3))) void* lvp;

__device__ __forceinline__ unsigned short f2bf(float f) {
    unsigned u = __float_as_uint(f);
    u += 0x7fffu + ((u >> 16) & 1u);   // RNE
    return (unsigned short)(u >> 16);
}

#define BAR()    do { asm volatile("" ::: "memory"); __builtin_amdgcn_s_barrier(); asm volatile("" ::: "memory"); } while (0)
#define WAITL()  do { asm volatile("s_waitcnt lgkmcnt(0)" ::: "memory"); __builtin_amdgcn_sched_barrier(0); } while (0)
#define WAITV4() asm volatile("s_waitcnt vmcnt(4)" ::: "memory")
#define WAITV0() asm volatile("s_waitcnt vmcnt(0)" ::: "memory")

// ---------------- conversion: X, Wv straight; Wq, Wk transposed (for G) ----------------
__global__ __launch_bounds__(256)
void cvt_all(const float* __restrict__ x, const float* __restrict__ wq,
             const float* __restrict__ wk, const float* __restrict__ wv,
             unsigned short* __restrict__ Xb, unsigned short* __restrict__ WqT,
             unsigned short* __restrict__ WkT, unsigned short* __restrict__ Wvb) {
    const int b = blockIdx.x, t = threadIdx.x;
    if (b < 2304) {
        const float* in; unsigned short* out; long base;
        if (b < 2048) { in = x;  out = Xb;  base = (long)b * 1024; }
        else          { in = wv; out = Wvb; base = (long)(b - 2048) * 1024; }
        #pragma unroll
        for (int k = 0; k < 4; ++k) {
            long idx = base + k * 256 + t;
            float4 v = reinterpret_cast<const float4*>(in)[idx];
            uint2 o;
            o.x = (unsigned)f2bf(v.x) | ((unsigned)f2bf(v.y) << 16);
            o.y = (unsigned)f2bf(v.z) | ((unsigned)f2bf(v.w) << 16);
            reinterpret_cast<uint2*>(out)[idx] = o;
        }
    } else {
        const int bb = b - 2304;
        const float* in = (bb < 256) ? wq : wk;
        unsigned short* out = (bb < 256) ? WqT : WkT;
        const int tile = bb & 255;
        const int e0 = (tile >> 4) * 64, d0 = (tile & 15) * 64;
        __shared__ unsigned short ldsT[64][68];
        const int r = t >> 4, cq = t & 15;
        #pragma unroll
        for (int p = 0; p < 4; ++p) {
            const int e = p * 16 + r;
            float4 v = *reinterpret_cast<const float4*>(in + (long)(e0 + e) * 1024 + d0 + cq * 4);
            ldsT[cq*4+0][e] = f2bf(v.x);
            ldsT[cq*4+1][e] = f2bf(v.y);
            ldsT[cq*4+2][e] = f2bf(v.z);
            ldsT[cq*4+3][e] = f2bf(v.w);
        }
        __syncthreads();
        #pragma unroll
        for (int p = 0; p < 4; ++p) {
            const int d = p * 16 + r;
            ushort4 o = *reinterpret_cast<const ushort4*>(&ldsT[d][cq * 4]);
            *reinterpret_cast<ushort4*>(out + (long)(d0 + d) * 1024 + e0 + cq * 4) = o;
        }
    }
}

// ===================== 128x128 engine pieces (T2 swizzle) =====================
__device__ __forceinline__ void stage_tile(unsigned short* Abuf, unsigned short* Bbuf,
                                           const unsigned short* A, int lda,
                                           const unsigned short* B, int ldb, int k0,
                                           int wid, int srow, int piece) {
    #pragma unroll
    for (int i = 0; i < 4; ++i) {
        const int c = wid * 4 + i;
        const int row = c * 8 + srow;
        const int cs = (piece * 16) ^ ((row & 7) << 4);   // pre-swizzled source col
        __builtin_amdgcn_global_load_lds(
            (gvp)(reinterpret_cast<const char*>(A + (long)row * lda + k0) + cs),
            (lvp)(reinterpret_cast<char*>(Abuf) + c * 1024), 16, 0, 0);
        __builtin_amdgcn_global_load_lds(
            (gvp)(reinterpret_cast<const char*>(B + (long)row * ldb + k0) + cs),
            (lvp)(reinterpret_cast<char*>(Bbuf) + c * 1024), 16, 0, 0);
    }
}

__device__ __forceinline__ void compute_tile(floatx4 acc[4][4], const unsigned short* As,
                                             const unsigned short* Bs, int wm, int wn,
                                             int frow, int lane) {
    #pragma unroll
    for (int ks = 0; ks < 2; ++ks) {
        short8 af[4], bf[4];
        const int colb = ks * 64 + (lane >> 4) * 16;
        #pragma unroll
        for (int i = 0; i < 4; ++i) {
            const int ar = wm + i * 16 + frow;
            af[i] = *reinterpret_cast<const short8*>(
                reinterpret_cast<const char*>(As) + ar * 128 + (colb ^ ((ar & 7) << 4)));
            const int br = wn + i * 16 + frow;
            bf[i] = *reinterpret_cast<const short8*>(
                reinterpret_cast<const char*>(Bs) + br * 128 + (colb ^ ((br & 7) << 4)));
        }
        #pragma unroll
        for (int i = 0; i < 4; ++i)
            #pragma unroll
            for (int j = 0; j < 4; ++j)
                acc[i][j] = __builtin_amdgcn_mfma_f32_16x16x32_bf16(af[i], bf[j], acc[i][j], 0, 0, 0);
    }
}

// ---- G split-K chunk: Gw[bz] += WkT-tile x WqT-tile over k in [bz*256, bz*256+256) ----
__global__ __launch_bounds__(256, 2)
void g_chunk(const unsigned short* __restrict__ WkT, const unsigned short* __restrict__ WqT,
             float* __restrict__ Gw) {
    const int bx = blockIdx.x, by = blockIdx.y, bz = blockIdx.z;
    const unsigned short* A = WkT + (long)by * 128 * 1024;
    const unsigned short* B = WqT + (long)bx * 128 * 1024;

    __shared__ unsigned short As[2][128 * 64];
    __shared__ unsigned short Bs[2][128 * 64];

    const int tid = threadIdx.x, lane = tid & 63, wid = tid >> 6;
    const int srow = lane >> 3, piece = lane & 7;
    const int wm = (wid >> 1) * 64, wn = (wid & 1) * 64, frow = lane & 15;

    floatx4 acc[4][4] = {};
    const int kbase = bz * 256;

    stage_tile(As[0], Bs[0], A, 1024, B, 1024, kbase, wid, srow, piece);
    WAITV0(); BAR();
    int cur = 0;
    #pragma unroll 1
    for (int t = 0; t < 4; ++t) {
        if (t < 3)
            stage_tile(As[cur ^ 1], Bs[cur ^ 1], A, 1024, B, 1024, kbase + (t + 1) * 64,
                       wid, srow, piece);
        compute_tile(acc, As[cur], Bs[cur], wm, wn, frow, lane);
        WAITV0(); BAR();
        cur ^= 1;
    }

    float* Cb = Gw + (long)bz * (1 << 20) + (long)(by * 128) * 1024 + bx * 128;
    const int cr0 = wm + (lane >> 4) * 4;
    const int cc0 = wn + (lane & 15);
    #pragma unroll
    for (int i = 0; i < 4; ++i)
        #pragma unroll
        for (int j = 0; j < 4; ++j)
            #pragma unroll
            for (int r = 0; r < 4; ++r)
                Cb[(long)(cr0 + i * 16 + r) * 1024 + cc0 + j * 16] = acc[i][j][r];
}

// ---- reduce 4 G chunks -> bf16 G (scaled by 1/sqrt(1024)) ----
__global__ __launch_bounds__(256)
void reduce_g(const float* __restrict__ Gw, unsigned short* __restrict__ Gp) {
    const long i4 = (long)blockIdx.x * 256 + threadIdx.x;
    const long M4 = (1l << 20) / 4;
    float4 a = reinterpret_cast<const float4*>(Gw)[i4];
    float4 b = reinterpret_cast<const float4*>(Gw)[i4 + M4];
    float4 c = reinterpret_cast<const float4*>(Gw)[i4 + 2 * M4];
    float4 d = reinterpret_cast<const float4*>(Gw)[i4 + 3 * M4];
    float sx = (a.x + b.x + c.x + d.x) * 0.03125f;
    float sy = (a.y + b.y + c.y + d.y) * 0.03125f;
    float sz = (a.z + b.z + c.z + d.z) * 0.03125f;
    float sw = (a.w + b.w + c.w + d.w) * 0.03125f;
    uint2 o;
    o.x = (unsigned)f2bf(sx) | ((unsigned)f2bf(sy) << 16);
    o.y = (unsigned)f2bf(sz) | ((unsigned)f2bf(sw) << 16);
    reinterpret_cast<uint2*>(Gp)[i4] = o;
}

// ---- PV: complementary pairing, depth-1 dbuf, XCD-owned (bz, v-half) for L2 residency ----
// XCD x (= original flat % 8) owns bz = x>>1 and v-rows [(x&1)*512, (x&1)*512+512):
// its 2MB Vt slice stays L2-resident; the 4 bx-sharers of each P row-block are
// co-resident on the same XCD with identical step schedules -> P read once from L3.
__global__ __launch_bounds__(256, 2)
void pv_pair(const unsigned short* __restrict__ P, const unsigned short* __restrict__ Vt,
             float* __restrict__ out) {
    const int flat = (blockIdx.z * 8 + blockIdx.y) * 8 + blockIdx.x;
    const int xcd = flat & 7, lid = flat >> 3;
    const int bz = xcd >> 1;
    const int bx = (xcd & 1) * 4 + (lid & 3);
    const int pj = lid >> 2;

    const unsigned short* Pb = P + (long)bz * 2048 * 4096;   // bf16 view of f32 rows
    const unsigned short* Bv = Vt + (long)bz * 1024 * 2048 + (long)(bx * 128) * 2048;
    float* Cb = out + (long)bz * 2048 * 1024;

    __shared__ unsigned short As[2][128 * 64];
    __shared__ unsigned short Bs[2][128 * 64];

    const int tid = threadIdx.x, lane = tid & 63, wid = tid >> 6;
    const int srow = lane >> 3, piece = lane & 7;
    const int wm = (wid >> 1) * 64, wn = (wid & 1) * 64, frow = lane & 15;

    #pragma unroll 1
    for (int j = 0; j < 2; ++j) {
        const int by = j ? 15 - pj : pj;
        const unsigned short* A = Pb + (long)by * 128 * 4096;
        const int nt = (by + 1) * 2;   // K-tiles of 64

        floatx4 acc[4][4] = {};
        stage_tile(As[0], Bs[0], A, 4096, Bv, 2048, 0, wid, srow, piece);
        WAITV0(); BAR();
        int cur = 0;
        #pragma unroll 1
        for (int t = 0; t < nt; ++t) {
            if (t + 1 < nt)
                stage_tile(As[cur ^ 1], Bs[cur ^ 1], A, 4096, Bv, 2048, (t + 1) * 64,
                           wid, srow, piece);
            compute_tile(acc, As[cur], Bs[cur], wm, wn, frow, lane);
            WAITV0(); BAR();
            cur ^= 1;
        }

        float* Cj = Cb + (long)(by * 128) * 1024 + bx * 128;
        const int cr0 = wm + (lane >> 4) * 4;
        const int cc0 = wn + (lane & 15);
        #pragma unroll
        for (int i = 0; i < 4; ++i)
            #pragma unroll
            for (int jj = 0; jj < 4; ++jj)
                #pragma unroll
                for (int r = 0; r < 4; ++r)
                    Cj[(long)(cr0 + i * 16 + r) * 1024 + cc0 + jj * 16] = acc[i][jj][r];
    }
}

// ===================== 256x256 8-phase GEMM =====================
__device__ __forceinline__ void stage_half(char* slot, const unsigned short* src,
                                           int ld, int k0, int tid) {
    #pragma unroll
    for (int r = 0; r < 2; ++r) {
        const int c = r * 512 + tid;
        const int row = c >> 3;
        const int cs = ((c & 7) * 16) ^ ((row & 7) << 4);
        const char* g = reinterpret_cast<const char*>(src + (long)row * ld + k0) + cs;
        __builtin_amdgcn_global_load_lds((gvp)g,
            (lvp)(slot + r * 8192 + (tid >> 6) * 1024), 16, 0, 0);
    }
}

__device__ __forceinline__ void load_a4(short8 a_[4][2], const char* slot, int mh,
                                        int fr, int csw0, int csw1) {
    #pragma unroll
    for (int i = 0; i < 4; ++i) {
        const int rb = (mh * 64 + i * 16 + fr) * 128;
        a_[i][0] = *reinterpret_cast<const short8*>(slot + rb + csw0);
        a_[i][1] = *reinterpret_cast<const short8*>(slot + rb + csw1);
    }
}

__device__ __forceinline__ void load_b2(short8 b_[2][2], const char* slot, int rbase,
                                        int nh, int fr, int csw0, int csw1) {
    #pragma unroll
    for (int j = 0; j < 2; ++j) {
        const int rb = (rbase + nh * 32 + j * 16 + fr) * 128;
        b_[j][0] = *reinterpret_cast<const short8*>(slot + rb + csw0);
        b_[j][1] = *reinterpret_cast<const short8*>(slot + rb + csw1);
    }
}

__device__ __forceinline__ void mfma16(floatx4 acc[8][4], short8 a_[4][2],
                                       short8 b_[2][2], int mh, int nh) {
    __builtin_amdgcn_s_setprio(1);
    #pragma unroll
    for (int i = 0; i < 4; ++i)
        #pragma unroll
        for (int j = 0; j < 2; ++j) {
            acc[mh*4+i][nh*2+j] = __builtin_amdgcn_mfma_f32_16x16x32_bf16(
                a_[i][0], b_[j][0], acc[mh*4+i][nh*2+j], 0, 0, 0);
            acc[mh*4+i][nh*2+j] = __builtin_amdgcn_mfma_f32_16x16x32_bf16(
                a_[i][1], b_[j][1], acc[mh*4+i][nh*2+j], 0, 0, 0);
        }
    __builtin_amdgcn_s_setprio(0);
}

// MODE 1: causal tile skip (scores). MODE 3: dual job Y/V with X-row XCD co-location.
template<typename CT, int MODE>
__global__ __launch_bounds__(512, 2)
void gemm8p(const unsigned short* __restrict__ A, const unsigned short* B,
            const unsigned short* B1, CT* __restrict__ C, unsigned short* __restrict__ Vt,
            int K, int lda, int ldb, int ldc,
            long sA, long sB, long sC, int nwg)
{
    const int gx = gridDim.x, gy = gridDim.y;
    int flat = (blockIdx.z * gy + blockIdx.y) * gx + blockIdx.x;
    int bx, by, bz = 0;
    bool isV = false;
    if (MODE == 1) {
        // T1 bijective remap
        int xcd = flat & 7, lid = flat >> 3;
        int q = nwg >> 3, r = nwg & 7;
        flat = (xcd < r ? xcd * (q + 1) : r * (q + 1) + (xcd - r) * q) + lid;
        bx = flat % gx;
        int t2 = flat / gx;
        by = t2 % gy;
        bz = t2 / gy;
        if (bx > by) return;
    } else {
        // MODE 3: XCD x owns X row-blocks {x, x+8, x+16, x+24}; all 8 sharers
        // (4 bx x {Y,V}) of a row-block co-located -> X fetched once per XCD.
        const int xcd = flat & 7, lid = flat >> 3;
        by = xcd + ((lid >> 3) << 3);
        const int sub = lid & 7;
        isV = (sub >> 2) != 0;
        bx = sub & 3;
        if (isV) B = B1;
    }

    A += (long)bz * sA + (long)by * 256 * lda;
    B += (long)bz * sB + (long)bx * 256 * ldb;
    C += (long)bz * sC;

    __shared__ __align__(16) char lds[8 * 16384];
    #define SLOT(db, op, half) (lds + ((((db) << 1 | (op)) << 1 | (half)) * 16384))

    const int tid  = threadIdx.x;
    const int lane = tid & 63;
    const int wid  = tid >> 6;
    const int wm = wid >> 2;
    const int wn = wid & 3;
    const int bh = wn >> 1;
    const int brbase = (wn & 1) * 64;
    const int fr = lane & 15;
    const int csw0 = ((lane >> 4) * 16) ^ ((fr & 7) << 4);
    const int csw1 = (64 + (lane >> 4) * 16) ^ ((fr & 7) << 4);

    const unsigned short* Ah[2] = { A, A + 128ll * lda };
    const unsigned short* Bh[2] = { B, B + 128ll * ldb };

    const int NT = K >> 6;
    const int NI = NT >> 1;

    floatx4 acc[8][4] = {};
    short8 a_[4][2];
    short8 b_[2][2][2];

    stage_half(SLOT(0,1,0), Bh[0], ldb, 0, tid);
    stage_half(SLOT(0,1,1), Bh[1], ldb, 0, tid);
    stage_half(SLOT(0,0,0), Ah[0], lda, 0, tid);
    stage_half(SLOT(0,0,1), Ah[1], lda, 0, tid);
    stage_half(SLOT(1,1,0), Bh[0], ldb, 64, tid);
    stage_half(SLOT(1,1,1), Bh[1], ldb, 64, tid);
    WAITV4();
    BAR();

    for (int I = 0; I < NI; ++I) {
        const int kA1 = min(2*I + 1, NT - 1) * 64;
        const int kT2 = min(2*I + 2, NT - 1) * 64;
        const int kB3 = min(2*I + 3, NT - 1) * 64;

        load_a4(a_, SLOT(0,0,wm), 0, fr, csw0, csw1);
        load_b2(b_[0], SLOT(0,1,bh), brbase, 0, fr, csw0, csw1);
        stage_half(SLOT(1,0,0), Ah[0], lda, kA1, tid);
        BAR(); WAITL();
        mfma16(acc, a_, b_[0], 0, 0);
        BAR();

        load_b2(b_[1], SLOT(0,1,bh), brbase, 1, fr, csw0, csw1);
        stage_half(SLOT(1,0,1), Ah[1], lda, kA1, tid);
        BAR(); WAITL();
        mfma16(acc, a_, b_[1], 0, 1);
        BAR();

        load_a4(a_, SLOT(0,0,wm), 1, fr, csw0, csw1);
        stage_half(SLOT(0,1,0), Bh[0], ldb, kT2, tid);
        BAR(); WAITL();
        mfma16(acc, a_, b_[1], 1, 1);
        BAR();

        stage_half(SLOT(0,1,1), Bh[1], ldb, kT2, tid);
        BAR(); WAITL();
        mfma16(acc, a_, b_[0], 1, 0);
        WAITV4();
        BAR();

        load_a4(a_, SLOT(1,0,wm), 0, fr, csw0, csw1);
        load_b2(b_[0], SLOT(1,1,bh), brbase, 0, fr, csw0, csw1);
        stage_half(SLOT(0,0,0), Ah[0], lda, kT2, tid);
        BAR(); WAITL();
        mfma16(acc, a_, b_[0], 0, 0);
        BAR();

        load_b2(b_[1], SLOT(1,1,bh), brbase, 1, fr, csw0, csw1);
        stage_half(SLOT(0,0,1), Ah[1], lda, kT2, tid);
        BAR(); WAITL();
        mfma16(acc, a_, b_[1], 0, 1);
        BAR();

        load_a4(a_, SLOT(1,0,wm), 1, fr, csw0, csw1);
        stage_half(SLOT(1,1,0), Bh[0], ldb, kB3, tid);
        BAR(); WAITL();
        mfma16(acc, a_, b_[1], 1, 1);
        BAR();

        stage_half(SLOT(1,1,1), Bh[1], ldb, kB3, tid);
        BAR(); WAITL();
        mfma16(acc, a_, b_[0], 1, 0);
        WAITV4();
        BAR();
    }

    if (MODE == 3 && isV) {
        WAITV0();
        BAR();
        char* T = lds;
        #pragma unroll
        for (int i = 0; i < 8; ++i)
            #pragma unroll
            for (int j = 0; j < 4; ++j) {
                const int n = wn * 64 + j * 16 + fr;
                const int m = wm * 128 + ((lane >> 4) << 2) + i * 16;
                uint2 pk;
                pk.x = (unsigned)f2bf(acc[i][j][0]) | ((unsigned)f2bf(acc[i][j][1]) << 16);
                pk.y = (unsigned)f2bf(acc[i][j][2]) | ((unsigned)f2bf(acc[i][j][3]) << 16);
                *reinterpret_cast<uint2*>(T + n * 512 + ((m * 2) ^ ((n & 7) << 4))) = pk;
            }
        __syncthreads();
        const int b  = by >> 3;
        const int s0 = (by & 7) * 256;
        #pragma unroll
        for (int c = 0; c < 16; ++c) {
            const int idx = c * 512 + tid;
            const int n = idx >> 5, k = idx & 31;
            uint4 v = *reinterpret_cast<const uint4*>(T + n * 512 + ((k * 16) ^ ((n & 7) << 4)));
            *reinterpret_cast<uint4*>(Vt + (long)b * (1024 * 2048)
                + (long)(bx * 256 + n) * 2048 + s0 + k * 8) = v;
        }
        return;
    }

    const int cr0 = by * 256 + wm * 128 + (lane >> 4) * 4;
    const int cc0 = bx * 256 + wn * 64 + (lane & 15);
    #pragma unroll
    for (int i = 0; i < 8; ++i)
        #pragma unroll
        for (int j = 0; j < 4; ++j)
            #pragma unroll
            for (int r = 0; r < 4; ++r) {
                long idx = (long)(cr0 + i * 16 + r) * ldc + (cc0 + j * 16);
                float v = acc[i][j][r];
                if constexpr (sizeof(CT) == 4) C[idx] = v;
                else                           C[idx] = (CT)f2bf(v);
            }
    #undef SLOT
}

// ---------------- causal softmax, row-paired (q, 2047-q): uniform work ----------------
__global__ __launch_bounds__(256)
void softmax_causal(float* __restrict__ Sc) {
    const int b = blockIdx.y;
    const int t = threadIdx.x;
    const int lane = t & 63, wid = t >> 6;
    __shared__ float rmax[2][4], rsum[2][4];

    #pragma unroll 1
    for (int h = 0; h < 2; ++h) {
        const int q = h ? 2047 - blockIdx.x : blockIdx.x;
        float* row = Sc + ((long)b * 2048 + q) * 2048;
        const int kend = (q | 127) + 1;

        float vals[8];
        float mx = -INFINITY;
        #pragma unroll
        for (int i = 0; i < 2; ++i) {
            const int c0 = i * 1024 + t * 4;
            if (c0 <= q) {
                float4 v = *reinterpret_cast<const float4*>(row + c0);
                float tmp[4] = {v.x, v.y, v.z, v.w};
                #pragma unroll
                for (int j = 0; j < 4; ++j) {
                    float val = (c0 + j <= q) ? tmp[j] : -INFINITY;
                    vals[i * 4 + j] = val;
                    mx = fmaxf(mx, val);
                }
            } else {
                vals[i*4+0] = vals[i*4+1] = vals[i*4+2] = vals[i*4+3] = -INFINITY;
            }
        }
        #pragma unroll
        for (int o = 32; o > 0; o >>= 1) mx = fmaxf(mx, __shfl_xor(mx, o));
        if (lane == 0) rmax[h][wid] = mx;
        __syncthreads();
        mx = fmaxf(fmaxf(rmax[h][0], rmax[h][1]), fmaxf(rmax[h][2], rmax[h][3]));

        float s = 0.f;
        #pragma unroll
        for (int k = 0; k < 8; ++k) {
            float e = __expf(vals[k] - mx);
            vals[k] = e;
            s += e;
        }
        #pragma unroll
        for (int o = 32; o > 0; o >>= 1) s += __shfl_xor(s, o);
        if (lane == 0) rsum[h][wid] = s;
        __syncthreads();
        s = rsum[h][0] + rsum[h][1] + rsum[h][2] + rsum[h][3];
        const float inv = 1.f / s;

        unsigned short* orow = reinterpret_cast<unsigned short*>(row);
        #pragma unroll
        for (int i = 0; i < 2; ++i) {
            const int c0 = i * 1024 + t * 4;
            if (c0 < kend) {
                uint2 o;
                o.x = (unsigned)f2bf(vals[i*4+0] * inv) | ((unsigned)f2bf(vals[i*4+1] * inv) << 16);
                o.y = (unsigned)f2bf(vals[i*4+2] * inv) | ((unsigned)f2bf(vals[i*4+3] * inv) << 16);
                *reinterpret_cast<uint2*>(orow + c0) = o;
            }
        }
    }
}

extern "C" void kernel_launch(void* const* d_in, const int* in_sizes, int n_in,
                              void* d_out, int out_size, void* d_ws, size_t ws_size,
                              hipStream_t stream) {
    const float* x  = (const float*)d_in[0];
    const float* Wq = (const float*)d_in[1];
    const float* Wk = (const float*)d_in[2];
    const float* Wv = (const float*)d_in[3];
    float* out = (float*)d_out;

    // ws: Xb@0(16M) WqT@16M(2M) WkT@18M(2M) Wvb@20M(2M) Yb@22M(16M) G@38M(2M)
    //     Gw@40M(16M f32 partials) Vt@70M(16M) Sc@86M(64M)
    char* w = (char*)d_ws;
    unsigned short* Xb  = (unsigned short*)(w);
    unsigned short* WqT = (unsigned short*)(w + (16ll << 20));
    unsigned short* WkT = (unsigned short*)(w + (18ll << 20));
    unsigned short* Wvb = (unsigned short*)(w + (20ll << 20));
    unsigned short* Yb  = (unsigned short*)(w + (22ll << 20));
    unsigned short* Gp  = (unsigned short*)(w + (38ll << 20));
    float*          Gw  = (float*)(w + (40ll << 20));
    unsigned short* Vt  = (unsigned short*)(w + (70ll << 20));
    float* Sc = (float*)(w + (86ll << 20));

    dim3 blk(256);
    cvt_all<<<2816, blk, 0, stream>>>(x, Wq, Wk, Wv, Xb, WqT, WkT, Wvb);

    // G^T = (Wk^T Wq) split-K over 4 chunks, then reduce+scale to bf16
    g_chunk<<<dim3(8, 8, 4), blk, 0, stream>>>(WkT, WqT, Gw);
    reduce_g<<<1024, blk, 0, stream>>>(Gw, Gp);

    // Y = X*G AND V-proj (transposed write), XCD-co-located X row-blocks
    gemm8p<unsigned short, 3><<<dim3(256, 1, 1), dim3(512), 0, stream>>>(
        Xb, Gp, Wvb, Yb, Vt, 1024, 1024, 1024, 1024,
        0, 0, 0, 256);

    // scores = Y @ X^T (pre-scaled), causal tile skip
    gemm8p<float, 1><<<dim3(8, 8, 4), dim3(512), 0, stream>>>(
        Yb, Xb, nullptr, Sc, nullptr, 1024, 1024, 1024, 2048,
        2048ll * 1024, 2048ll * 1024, 2048ll * 2048, 256);

    softmax_causal<<<dim3(1024, 4), blk, 0, stream>>>(Sc);

    // out = P @ V  (complementary-paired, depth-1 dbuf, XCD-owned V slices)
    pv_pair<<<dim3(8, 8, 4), blk, 0, stream>>>((const unsigned short*)Sc, Vt, out);
}

// Round 9
// 140.704 us; speedup vs baseline: 1.0724x; 1.0210x over previous
//
#include <hip/hip_runtime.h>
#include <hip/hip_bf16.h>
#include <stdint.h>

typedef __attribute__((ext_vector_type(8))) short short8;
typedef __attribute__((ext_vector_type(4))) float floatx4;

typedef const __attribute__((address_space(1))) void* gvp;
typedef __attribute__((address_space(3))) void* lvp;

__device__ __forceinline__ unsigned short f2bf(float f) {
    unsigned u = __float_as_uint(f);
    u += 0x7fffu + ((u >> 16) & 1u);   // RNE
    return (unsigned short)(u >> 16);
}

#define BAR()    do { asm volatile("" ::: "memory"); __builtin_amdgcn_s_barrier(); asm volatile("" ::: "memory"); } while (0)
#define WAITL()  do { asm volatile("s_waitcnt lgkmcnt(0)" ::: "memory"); __builtin_amdgcn_sched_barrier(0); } while (0)
#define WAITV4() asm volatile("s_waitcnt vmcnt(4)" ::: "memory")
#define WAITV0() asm volatile("s_waitcnt vmcnt(0)" ::: "memory")

// ---------------- conversion: X, Wv straight; Wq, Wk transposed (for G) ----------------
__global__ __launch_bounds__(256)
void cvt_all(const float* __restrict__ x, const float* __restrict__ wq,
             const float* __restrict__ wk, const float* __restrict__ wv,
             unsigned short* __restrict__ Xb, unsigned short* __restrict__ WqT,
             unsigned short* __restrict__ WkT, unsigned short* __restrict__ Wvb) {
    const int b = blockIdx.x, t = threadIdx.x;
    if (b < 2304) {
        const float* in; unsigned short* out; long base;
        if (b < 2048) { in = x;  out = Xb;  base = (long)b * 1024; }
        else          { in = wv; out = Wvb; base = (long)(b - 2048) * 1024; }
        #pragma unroll
        for (int k = 0; k < 4; ++k) {
            long idx = base + k * 256 + t;
            float4 v = reinterpret_cast<const float4*>(in)[idx];
            uint2 o;
            o.x = (unsigned)f2bf(v.x) | ((unsigned)f2bf(v.y) << 16);
            o.y = (unsigned)f2bf(v.z) | ((unsigned)f2bf(v.w) << 16);
            reinterpret_cast<uint2*>(out)[idx] = o;
        }
    } else {
        const int bb = b - 2304;
        const float* in = (bb < 256) ? wq : wk;
        unsigned short* out = (bb < 256) ? WqT : WkT;
        const int tile = bb & 255;
        const int e0 = (tile >> 4) * 64, d0 = (tile & 15) * 64;
        __shared__ unsigned short ldsT[64][68];
        const int r = t >> 4, cq = t & 15;
        #pragma unroll
        for (int p = 0; p < 4; ++p) {
            const int e = p * 16 + r;
            float4 v = *reinterpret_cast<const float4*>(in + (long)(e0 + e) * 1024 + d0 + cq * 4);
            ldsT[cq*4+0][e] = f2bf(v.x);
            ldsT[cq*4+1][e] = f2bf(v.y);
            ldsT[cq*4+2][e] = f2bf(v.z);
            ldsT[cq*4+3][e] = f2bf(v.w);
        }
        __syncthreads();
        #pragma unroll
        for (int p = 0; p < 4; ++p) {
            const int d = p * 16 + r;
            ushort4 o = *reinterpret_cast<const ushort4*>(&ldsT[d][cq * 4]);
            *reinterpret_cast<ushort4*>(out + (long)(d0 + d) * 1024 + e0 + cq * 4) = o;
        }
    }
}

// ===================== 128x128 engine pieces (T2 swizzle) =====================
__device__ __forceinline__ void stage_tile(unsigned short* Abuf, unsigned short* Bbuf,
                                           const unsigned short* A, int lda,
                                           const unsigned short* B, int ldb, int k0,
                                           int wid, int srow, int piece) {
    #pragma unroll
    for (int i = 0; i < 4; ++i) {
        const int c = wid * 4 + i;
        const int row = c * 8 + srow;
        const int cs = (piece * 16) ^ ((row & 7) << 4);   // pre-swizzled source col
        __builtin_amdgcn_global_load_lds(
            (gvp)(reinterpret_cast<const char*>(A + (long)row * lda + k0) + cs),
            (lvp)(reinterpret_cast<char*>(Abuf) + c * 1024), 16, 0, 0);
        __builtin_amdgcn_global_load_lds(
            (gvp)(reinterpret_cast<const char*>(B + (long)row * ldb + k0) + cs),
            (lvp)(reinterpret_cast<char*>(Bbuf) + c * 1024), 16, 0, 0);
    }
}

__device__ __forceinline__ void compute_tile(floatx4 acc[4][4], const unsigned short* As,
                                             const unsigned short* Bs, int wm, int wn,
                                             int frow, int lane) {
    #pragma unroll
    for (int ks = 0; ks < 2; ++ks) {
        short8 af[4], bf[4];
        const int colb = ks * 64 + (lane >> 4) * 16;
        #pragma unroll
        for (int i = 0; i < 4; ++i) {
            const int ar = wm + i * 16 + frow;
            af[i] = *reinterpret_cast<const short8*>(
                reinterpret_cast<const char*>(As) + ar * 128 + (colb ^ ((ar & 7) << 4)));
            const int br = wn + i * 16 + frow;
            bf[i] = *reinterpret_cast<const short8*>(
                reinterpret_cast<const char*>(Bs) + br * 128 + (colb ^ ((br & 7) << 4)));
        }
        #pragma unroll
        for (int i = 0; i < 4; ++i)
            #pragma unroll
            for (int j = 0; j < 4; ++j)
                acc[i][j] = __builtin_amdgcn_mfma_f32_16x16x32_bf16(af[i], bf[j], acc[i][j], 0, 0, 0);
    }
}

// ---- G split-K chunk: Gw[bz] += WkT-tile x WqT-tile over k in [bz*256, bz*256+256) ----
__global__ __launch_bounds__(256, 2)
void g_chunk(const unsigned short* __restrict__ WkT, const unsigned short* __restrict__ WqT,
             float* __restrict__ Gw) {
    const int bx = blockIdx.x, by = blockIdx.y, bz = blockIdx.z;
    const unsigned short* A = WkT + (long)by * 128 * 1024;
    const unsigned short* B = WqT + (long)bx * 128 * 1024;

    __shared__ unsigned short As[2][128 * 64];
    __shared__ unsigned short Bs[2][128 * 64];

    const int tid = threadIdx.x, lane = tid & 63, wid = tid >> 6;
    const int srow = lane >> 3, piece = lane & 7;
    const int wm = (wid >> 1) * 64, wn = (wid & 1) * 64, frow = lane & 15;

    floatx4 acc[4][4] = {};
    const int kbase = bz * 256;

    stage_tile(As[0], Bs[0], A, 1024, B, 1024, kbase, wid, srow, piece);
    WAITV0(); BAR();
    int cur = 0;
    #pragma unroll 1
    for (int t = 0; t < 4; ++t) {
        if (t < 3)
            stage_tile(As[cur ^ 1], Bs[cur ^ 1], A, 1024, B, 1024, kbase + (t + 1) * 64,
                       wid, srow, piece);
        compute_tile(acc, As[cur], Bs[cur], wm, wn, frow, lane);
        WAITV0(); BAR();
        cur ^= 1;
    }

    float* Cb = Gw + (long)bz * (1 << 20) + (long)(by * 128) * 1024 + bx * 128;
    const int cr0 = wm + (lane >> 4) * 4;
    const int cc0 = wn + (lane & 15);
    #pragma unroll
    for (int i = 0; i < 4; ++i)
        #pragma unroll
        for (int j = 0; j < 4; ++j)
            #pragma unroll
            for (int r = 0; r < 4; ++r)
                Cb[(long)(cr0 + i * 16 + r) * 1024 + cc0 + j * 16] = acc[i][j][r];
}

// ---- reduce 4 G chunks -> bf16 G (scaled by 1/sqrt(1024)) ----
__global__ __launch_bounds__(256)
void reduce_g(const float* __restrict__ Gw, unsigned short* __restrict__ Gp) {
    const long i4 = (long)blockIdx.x * 256 + threadIdx.x;
    const long M4 = (1l << 20) / 4;
    float4 a = reinterpret_cast<const float4*>(Gw)[i4];
    float4 b = reinterpret_cast<const float4*>(Gw)[i4 + M4];
    float4 c = reinterpret_cast<const float4*>(Gw)[i4 + 2 * M4];
    float4 d = reinterpret_cast<const float4*>(Gw)[i4 + 3 * M4];
    float sx = (a.x + b.x + c.x + d.x) * 0.03125f;
    float sy = (a.y + b.y + c.y + d.y) * 0.03125f;
    float sz = (a.z + b.z + c.z + d.z) * 0.03125f;
    float sw = (a.w + b.w + c.w + d.w) * 0.03125f;
    uint2 o;
    o.x = (unsigned)f2bf(sx) | ((unsigned)f2bf(sy) << 16);
    o.y = (unsigned)f2bf(sz) | ((unsigned)f2bf(sw) << 16);
    reinterpret_cast<uint2*>(Gp)[i4] = o;
}

// ---- PV v3: temporal XCD schedule ----
// 512 blocks. XCD x = flat%8 owns (bz = x>>1, by-parity = x&1): 64 blocks =
// 8 by x 8 bx on 32 CUs at 2 blocks/CU, ALL co-resident and step-aligned:
// at step t every block reads V-slab [64t,64t+64) (shared, L2-hot) and the
// 8 bx-sharers of each P-tile hit L2 after the first fetch. Per-CU balance:
// lids c,c+32 -> g,g+4 with by-index gi(g)= g<4?g:11-g  (sums const).
__global__ __launch_bounds__(256, 2)
void pv_sched(const unsigned short* __restrict__ P, const unsigned short* __restrict__ Vt,
              float* __restrict__ out) {
    const int flat = (blockIdx.z * 8 + blockIdx.y) * 8 + blockIdx.x;   // 0..511
    const int xcd = flat & 7, lid = flat >> 3;
    const int bz = xcd >> 1, parity = xcd & 1;
    const int bx = lid & 7;
    const int g  = lid >> 3;
    const int gi = (g < 4) ? g : (11 - g);
    const int by = parity + 2 * gi;

    const unsigned short* Pb = P + (long)bz * 2048 * 4096;   // bf16 view of f32 rows
    const unsigned short* Bv = Vt + (long)bz * 1024 * 2048 + (long)(bx * 128) * 2048;
    const unsigned short* A = Pb + (long)by * 128 * 4096;
    float* Cb = out + (long)bz * 2048 * 1024;
    const int nt = (by + 1) * 2;   // K-tiles of 64

    __shared__ unsigned short As[2][128 * 64];
    __shared__ unsigned short Bs[2][128 * 64];

    const int tid = threadIdx.x, lane = tid & 63, wid = tid >> 6;
    const int srow = lane >> 3, piece = lane & 7;
    const int wm = (wid >> 1) * 64, wn = (wid & 1) * 64, frow = lane & 15;

    floatx4 acc[4][4] = {};
    stage_tile(As[0], Bs[0], A, 4096, Bv, 2048, 0, wid, srow, piece);
    WAITV0(); BAR();
    int cur = 0;
    #pragma unroll 1
    for (int t = 0; t < nt; ++t) {
        if (t + 1 < nt)
            stage_tile(As[cur ^ 1], Bs[cur ^ 1], A, 4096, Bv, 2048, (t + 1) * 64,
                       wid, srow, piece);
        compute_tile(acc, As[cur], Bs[cur], wm, wn, frow, lane);
        WAITV0(); BAR();
        cur ^= 1;
    }

    float* Cj = Cb + (long)(by * 128) * 1024 + bx * 128;
    const int cr0 = wm + (lane >> 4) * 4;
    const int cc0 = wn + (lane & 15);
    #pragma unroll
    for (int i = 0; i < 4; ++i)
        #pragma unroll
        for (int jj = 0; jj < 4; ++jj)
            #pragma unroll
            for (int r = 0; r < 4; ++r)
                Cj[(long)(cr0 + i * 16 + r) * 1024 + cc0 + jj * 16] = acc[i][jj][r];
}

// ===================== 256x256 8-phase GEMM =====================
__device__ __forceinline__ void stage_half(char* slot, const unsigned short* src,
                                           int ld, int k0, int tid) {
    #pragma unroll
    for (int r = 0; r < 2; ++r) {
        const int c = r * 512 + tid;
        const int row = c >> 3;
        const int cs = ((c & 7) * 16) ^ ((row & 7) << 4);
        const char* g = reinterpret_cast<const char*>(src + (long)row * ld + k0) + cs;
        __builtin_amdgcn_global_load_lds((gvp)g,
            (lvp)(slot + r * 8192 + (tid >> 6) * 1024), 16, 0, 0);
    }
}

__device__ __forceinline__ void load_a4(short8 a_[4][2], const char* slot, int mh,
                                        int fr, int csw0, int csw1) {
    #pragma unroll
    for (int i = 0; i < 4; ++i) {
        const int rb = (mh * 64 + i * 16 + fr) * 128;
        a_[i][0] = *reinterpret_cast<const short8*>(slot + rb + csw0);
        a_[i][1] = *reinterpret_cast<const short8*>(slot + rb + csw1);
    }
}

__device__ __forceinline__ void load_b2(short8 b_[2][2], const char* slot, int rbase,
                                        int nh, int fr, int csw0, int csw1) {
    #pragma unroll
    for (int j = 0; j < 2; ++j) {
        const int rb = (rbase + nh * 32 + j * 16 + fr) * 128;
        b_[j][0] = *reinterpret_cast<const short8*>(slot + rb + csw0);
        b_[j][1] = *reinterpret_cast<const short8*>(slot + rb + csw1);
    }
}

__device__ __forceinline__ void mfma16(floatx4 acc[8][4], short8 a_[4][2],
                                       short8 b_[2][2], int mh, int nh) {
    __builtin_amdgcn_s_setprio(1);
    #pragma unroll
    for (int i = 0; i < 4; ++i)
        #pragma unroll
        for (int j = 0; j < 2; ++j) {
            acc[mh*4+i][nh*2+j] = __builtin_amdgcn_mfma_f32_16x16x32_bf16(
                a_[i][0], b_[j][0], acc[mh*4+i][nh*2+j], 0, 0, 0);
            acc[mh*4+i][nh*2+j] = __builtin_amdgcn_mfma_f32_16x16x32_bf16(
                a_[i][1], b_[j][1], acc[mh*4+i][nh*2+j], 0, 0, 0);
        }
    __builtin_amdgcn_s_setprio(0);
}

// MODE 1: causal tile skip (scores). MODE 3: dual job Y/V with X-row XCD co-location.
template<typename CT, int MODE>
__global__ __launch_bounds__(512, 2)
void gemm8p(const unsigned short* __restrict__ A, const unsigned short* B,
            const unsigned short* B1, CT* __restrict__ C, unsigned short* __restrict__ Vt,
            int K, int lda, int ldb, int ldc,
            long sA, long sB, long sC, int nwg)
{
    const int gx = gridDim.x, gy = gridDim.y;
    int flat = (blockIdx.z * gy + blockIdx.y) * gx + blockIdx.x;
    int bx, by, bz = 0;
    bool isV = false;
    if (MODE == 1) {
        int xcd = flat & 7, lid = flat >> 3;
        int q = nwg >> 3, r = nwg & 7;
        flat = (xcd < r ? xcd * (q + 1) : r * (q + 1) + (xcd - r) * q) + lid;
        bx = flat % gx;
        int t2 = flat / gx;
        by = t2 % gy;
        bz = t2 / gy;
        if (bx > by) return;
    } else {
        const int xcd = flat & 7, lid = flat >> 3;
        by = xcd + ((lid >> 3) << 3);
        const int sub = lid & 7;
        isV = (sub >> 2) != 0;
        bx = sub & 3;
        if (isV) B = B1;
    }

    A += (long)bz * sA + (long)by * 256 * lda;
    B += (long)bz * sB + (long)bx * 256 * ldb;
    C += (long)bz * sC;

    __shared__ __align__(16) char lds[8 * 16384];
    #define SLOT(db, op, half) (lds + ((((db) << 1 | (op)) << 1 | (half)) * 16384))

    const int tid  = threadIdx.x;
    const int lane = tid & 63;
    const int wid  = tid >> 6;
    const int wm = wid >> 2;
    const int wn = wid & 3;
    const int bh = wn >> 1;
    const int brbase = (wn & 1) * 64;
    const int fr = lane & 15;
    const int csw0 = ((lane >> 4) * 16) ^ ((fr & 7) << 4);
    const int csw1 = (64 + (lane >> 4) * 16) ^ ((fr & 7) << 4);

    const unsigned short* Ah[2] = { A, A + 128ll * lda };
    const unsigned short* Bh[2] = { B, B + 128ll * ldb };

    const int NT = K >> 6;
    const int NI = NT >> 1;

    floatx4 acc[8][4] = {};
    short8 a_[4][2];
    short8 b_[2][2][2];

    stage_half(SLOT(0,1,0), Bh[0], ldb, 0, tid);
    stage_half(SLOT(0,1,1), Bh[1], ldb, 0, tid);
    stage_half(SLOT(0,0,0), Ah[0], lda, 0, tid);
    stage_half(SLOT(0,0,1), Ah[1], lda, 0, tid);
    stage_half(SLOT(1,1,0), Bh[0], ldb, 64, tid);
    stage_half(SLOT(1,1,1), Bh[1], ldb, 64, tid);
    WAITV4();
    BAR();

    for (int I = 0; I < NI; ++I) {
        const int kA1 = min(2*I + 1, NT - 1) * 64;
        const int kT2 = min(2*I + 2, NT - 1) * 64;
        const int kB3 = min(2*I + 3, NT - 1) * 64;

        load_a4(a_, SLOT(0,0,wm), 0, fr, csw0, csw1);
        load_b2(b_[0], SLOT(0,1,bh), brbase, 0, fr, csw0, csw1);
        stage_half(SLOT(1,0,0), Ah[0], lda, kA1, tid);
        BAR(); WAITL();
        mfma16(acc, a_, b_[0], 0, 0);
        BAR();

        load_b2(b_[1], SLOT(0,1,bh), brbase, 1, fr, csw0, csw1);
        stage_half(SLOT(1,0,1), Ah[1], lda, kA1, tid);
        BAR(); WAITL();
        mfma16(acc, a_, b_[1], 0, 1);
        BAR();

        load_a4(a_, SLOT(0,0,wm), 1, fr, csw0, csw1);
        stage_half(SLOT(0,1,0), Bh[0], ldb, kT2, tid);
        BAR(); WAITL();
        mfma16(acc, a_, b_[1], 1, 1);
        BAR();

        stage_half(SLOT(0,1,1), Bh[1], ldb, kT2, tid);
        BAR(); WAITL();
        mfma16(acc, a_, b_[0], 1, 0);
        WAITV4();
        BAR();

        load_a4(a_, SLOT(1,0,wm), 0, fr, csw0, csw1);
        load_b2(b_[0], SLOT(1,1,bh), brbase, 0, fr, csw0, csw1);
        stage_half(SLOT(0,0,0), Ah[0], lda, kT2, tid);
        BAR(); WAITL();
        mfma16(acc, a_, b_[0], 0, 0);
        BAR();

        load_b2(b_[1], SLOT(1,1,bh), brbase, 1, fr, csw0, csw1);
        stage_half(SLOT(0,0,1), Ah[1], lda, kT2, tid);
        BAR(); WAITL();
        mfma16(acc, a_, b_[1], 0, 1);
        BAR();

        load_a4(a_, SLOT(1,0,wm), 1, fr, csw0, csw1);
        stage_half(SLOT(1,1,0), Bh[0], ldb, kB3, tid);
        BAR(); WAITL();
        mfma16(acc, a_, b_[1], 1, 1);
        BAR();

        stage_half(SLOT(1,1,1), Bh[1], ldb, kB3, tid);
        BAR(); WAITL();
        mfma16(acc, a_, b_[0], 1, 0);
        WAITV4();
        BAR();
    }

    if (MODE == 3 && isV) {
        WAITV0();
        BAR();
        char* T = lds;
        #pragma unroll
        for (int i = 0; i < 8; ++i)
            #pragma unroll
            for (int j = 0; j < 4; ++j) {
                const int n = wn * 64 + j * 16 + fr;
                const int m = wm * 128 + ((lane >> 4) << 2) + i * 16;
                uint2 pk;
                pk.x = (unsigned)f2bf(acc[i][j][0]) | ((unsigned)f2bf(acc[i][j][1]) << 16);
                pk.y = (unsigned)f2bf(acc[i][j][2]) | ((unsigned)f2bf(acc[i][j][3]) << 16);
                *reinterpret_cast<uint2*>(T + n * 512 + ((m * 2) ^ ((n & 7) << 4))) = pk;
            }
        __syncthreads();
        const int b  = by >> 3;
        const int s0 = (by & 7) * 256;
        #pragma unroll
        for (int c = 0; c < 16; ++c) {
            const int idx = c * 512 + tid;
            const int n = idx >> 5, k = idx & 31;
            uint4 v = *reinterpret_cast<const uint4*>(T + n * 512 + ((k * 16) ^ ((n & 7) << 4)));
            *reinterpret_cast<uint4*>(Vt + (long)b * (1024 * 2048)
                + (long)(bx * 256 + n) * 2048 + s0 + k * 8) = v;
        }
        return;
    }

    const int cr0 = by * 256 + wm * 128 + (lane >> 4) * 4;
    const int cc0 = bx * 256 + wn * 64 + (lane & 15);
    #pragma unroll
    for (int i = 0; i < 8; ++i)
        #pragma unroll
        for (int j = 0; j < 4; ++j)
            #pragma unroll
            for (int r = 0; r < 4; ++r) {
                long idx = (long)(cr0 + i * 16 + r) * ldc + (cc0 + j * 16);
                float v = acc[i][j][r];
                if constexpr (sizeof(CT) == 4) C[idx] = v;
                else                           C[idx] = (CT)f2bf(v);
            }
    #undef SLOT
}

// ---------------- causal softmax, row-paired (q, 2047-q): uniform work ----------------
__global__ __launch_bounds__(256)
void softmax_causal(float* __restrict__ Sc) {
    const int b = blockIdx.y;
    const int t = threadIdx.x;
    const int lane = t & 63, wid = t >> 6;
    __shared__ float rmax[2][4], rsum[2][4];

    #pragma unroll 1
    for (int h = 0; h < 2; ++h) {
        const int q = h ? 2047 - blockIdx.x : blockIdx.x;
        float* row = Sc + ((long)b * 2048 + q) * 2048;
        const int kend = (q | 127) + 1;

        float vals[8];
        float mx = -INFINITY;
        #pragma unroll
        for (int i = 0; i < 2; ++i) {
            const int c0 = i * 1024 + t * 4;
            if (c0 <= q) {
                float4 v = *reinterpret_cast<const float4*>(row + c0);
                float tmp[4] = {v.x, v.y, v.z, v.w};
                #pragma unroll
                for (int j = 0; j < 4; ++j) {
                    float val = (c0 + j <= q) ? tmp[j] : -INFINITY;
                    vals[i * 4 + j] = val;
                    mx = fmaxf(mx, val);
                }
            } else {
                vals[i*4+0] = vals[i*4+1] = vals[i*4+2] = vals[i*4+3] = -INFINITY;
            }
        }
        #pragma unroll
        for (int o = 32; o > 0; o >>= 1) mx = fmaxf(mx, __shfl_xor(mx, o));
        if (lane == 0) rmax[h][wid] = mx;
        __syncthreads();
        mx = fmaxf(fmaxf(rmax[h][0], rmax[h][1]), fmaxf(rmax[h][2], rmax[h][3]));

        float s = 0.f;
        #pragma unroll
        for (int k = 0; k < 8; ++k) {
            float e = __expf(vals[k] - mx);
            vals[k] = e;
            s += e;
        }
        #pragma unroll
        for (int o = 32; o > 0; o >>= 1) s += __shfl_xor(s, o);
        if (lane == 0) rsum[h][wid] = s;
        __syncthreads();
        s = rsum[h][0] + rsum[h][1] + rsum[h][2] + rsum[h][3];
        const float inv = 1.f / s;

        unsigned short* orow = reinterpret_cast<unsigned short*>(row);
        #pragma unroll
        for (int i = 0; i < 2; ++i) {
            const int c0 = i * 1024 + t * 4;
            if (c0 < kend) {
                uint2 o;
                o.x = (unsigned)f2bf(vals[i*4+0] * inv) | ((unsigned)f2bf(vals[i*4+1] * inv) << 16);
                o.y = (unsigned)f2bf(vals[i*4+2] * inv) | ((unsigned)f2bf(vals[i*4+3] * inv) << 16);
                *reinterpret_cast<uint2*>(orow + c0) = o;
            }
        }
    }
}

extern "C" void kernel_launch(void* const* d_in, const int* in_sizes, int n_in,
                              void* d_out, int out_size, void* d_ws, size_t ws_size,
                              hipStream_t stream) {
    const float* x  = (const float*)d_in[0];
    const float* Wq = (const float*)d_in[1];
    const float* Wk = (const float*)d_in[2];
    const float* Wv = (const float*)d_in[3];
    float* out = (float*)d_out;

    // ws: Xb@0(16M) WqT@16M(2M) WkT@18M(2M) Wvb@20M(2M) Yb@22M(16M) G@38M(2M)
    //     Gw@40M(16M f32 partials) Vt@70M(16M) Sc@86M(64M)
    char* w = (char*)d_ws;
    unsigned short* Xb  = (unsigned short*)(w);
    unsigned short* WqT = (unsigned short*)(w + (16ll << 20));
    unsigned short* WkT = (unsigned short*)(w + (18ll << 20));
    unsigned short* Wvb = (unsigned short*)(w + (20ll << 20));
    unsigned short* Yb  = (unsigned short*)(w + (22ll << 20));
    unsigned short* Gp  = (unsigned short*)(w + (38ll << 20));
    float*          Gw  = (float*)(w + (40ll << 20));
    unsigned short* Vt  = (unsigned short*)(w + (70ll << 20));
    float* Sc = (float*)(w + (86ll << 20));

    dim3 blk(256);
    cvt_all<<<2816, blk, 0, stream>>>(x, Wq, Wk, Wv, Xb, WqT, WkT, Wvb);

    // G^T = (Wk^T Wq) split-K over 4 chunks, then reduce+scale to bf16
    g_chunk<<<dim3(8, 8, 4), blk, 0, stream>>>(WkT, WqT, Gw);
    reduce_g<<<1024, blk, 0, stream>>>(Gw, Gp);

    // Y = X*G AND V-proj (transposed write), XCD-co-located X row-blocks
    gemm8p<unsigned short, 3><<<dim3(256, 1, 1), dim3(512), 0, stream>>>(
        Xb, Gp, Wvb, Yb, Vt, 1024, 1024, 1024, 1024,
        0, 0, 0, 256);

    // scores = Y @ X^T (pre-scaled), causal tile skip
    gemm8p<float, 1><<<dim3(8, 8, 4), dim3(512), 0, stream>>>(
        Yb, Xb, nullptr, Sc, nullptr, 1024, 1024, 1024, 2048,
        2048ll * 1024, 2048ll * 1024, 2048ll * 2048, 256);

    softmax_causal<<<dim3(1024, 4), blk, 0, stream>>>(Sc);

    // out = P @ V  (temporal XCD schedule: co-resident step-aligned sharers)
    pv_sched<<<dim3(8, 8, 8), blk, 0, stream>>>((const unsigned short*)Sc, Vt, out);
}